// Round 12
// baseline (106.846 us; speedup 1.0000x reference)
//
#include <hip/hip_runtime.h>
#include <math.h>

#define S_NEI 32

// ---------------- transpose 256x256 (WkT[e][f] = Wk[f][e]) ----------------
__global__ __launch_bounds__(256) void transpose256(const float* __restrict__ in,
                                                    float* __restrict__ outT) {
    __shared__ float tile[32][33];
    const int bx = blockIdx.x * 32, by = blockIdx.y * 32;
    const int x = threadIdx.x, y = threadIdx.y;  // 32 x 8
#pragma unroll
    for (int i = 0; i < 32; i += 8)
        tile[y + i][x] = in[(by + y + i) * 256 + bx + x];
    __syncthreads();
#pragma unroll
    for (int i = 0; i < 32; i += 8)
        outT[(bx + y + i) * 256 + by + x] = tile[x][y + i];
}

// ---------------- legacy 8x256 tile GEMM (for tiny precompute GEMMs) -------
template <int KT>
__device__ __forceinline__ void gemm_tile8(const float* __restrict__ A, int row0,
                                           const float* __restrict__ B,
                                           float acc[2][4], float* __restrict__ sA,
                                           float* __restrict__ sB) {
    const int t = threadIdx.x;
    const int tr = t >> 6, tc = t & 63;
    const int r = t >> 5;
    const int k1 = t & 31;
    const size_t arow = (size_t)(row0 + r) * KT;
    for (int kb = 0; kb < KT; kb += 32) {
        sA[k1 * 12 + r] = A[arow + kb + k1];
#pragma unroll
        for (int i = 0; i < 8; ++i) {
            *reinterpret_cast<float4*>(&sB[(i * 4 + tr) * 256 + tc * 4]) =
                *reinterpret_cast<const float4*>(&B[(size_t)(kb + i * 4 + tr) * 256 + tc * 4]);
        }
        __syncthreads();
#pragma unroll
        for (int k = 0; k < 32; ++k) {
            const float2 a2 = *reinterpret_cast<const float2*>(&sA[k * 12 + tr * 2]);
            const float4 b4 = *reinterpret_cast<const float4*>(&sB[k * 256 + tc * 4]);
            acc[0][0] += a2.x * b4.x; acc[0][1] += a2.x * b4.y;
            acc[0][2] += a2.x * b4.z; acc[0][3] += a2.x * b4.w;
            acc[1][0] += a2.y * b4.x; acc[1][1] += a2.y * b4.y;
            acc[1][2] += a2.y * b4.z; acc[1][3] += a2.y * b4.w;
        }
        __syncthreads();
    }
}

// Wqk=Wq@WkT, Wvc=Wv@Wc_top, Wmc=Wm@Wc_bot
__global__ __launch_bounds__(256) void precompute3(const float* __restrict__ Wq,
                                                   const float* __restrict__ Wv,
                                                   const float* __restrict__ Wm,
                                                   const float* __restrict__ Wc,
                                                   const float* __restrict__ WkT,
                                                   float* __restrict__ Wqk,
                                                   float* __restrict__ Wvc,
                                                   float* __restrict__ Wmc) {
    __shared__ float sA[32 * 12];
    __shared__ float sB[32 * 256];
    float acc[2][4] = {};
    const float *Ap, *Bp;
    float* Cp;
    switch (blockIdx.y) {
        case 0: Ap = Wq; Bp = WkT; Cp = Wqk; break;
        case 1: Ap = Wv; Bp = Wc; Cp = Wvc; break;
        default: Ap = Wm; Bp = Wc + 256 * 256; Cp = Wmc; break;
    }
    const int row0 = blockIdx.x * 8;
    gemm_tile8<256>(Ap, row0, Bp, acc, sA, sB);
    const int tr = threadIdx.x >> 6, tc = threadIdx.x & 63;
#pragma unroll
    for (int i = 0; i < 2; ++i) {
        float4 v = make_float4(acc[i][0], acc[i][1], acc[i][2], acc[i][3]);
        *reinterpret_cast<float4*>(&Cp[(row0 + tr * 2 + i) * 256 + tc * 4]) = v;
    }
}

// bqk = bq@WkT ; bfull = bv@Wc_top + bm@Wc_bot + bc  (block per column)
__global__ __launch_bounds__(256) void bias_k(const float* __restrict__ bq,
                                              const float* __restrict__ bv,
                                              const float* __restrict__ bm,
                                              const float* __restrict__ bc,
                                              const float* __restrict__ Wc,
                                              const float* __restrict__ WkT,
                                              float* __restrict__ bqk,
                                              float* __restrict__ bfull) {
    const int c = blockIdx.x;
    const int e = threadIdx.x;
    const int w = e >> 6, l = e & 63;
    float a = bq[e] * WkT[e * 256 + c];
    float v = bv[e] * Wc[e * 256 + c] + bm[e] * Wc[(256 + e) * 256 + c];
    __shared__ float redA[4], redV[4];
#pragma unroll
    for (int off = 32; off; off >>= 1) { a += __shfl_xor(a, off); v += __shfl_xor(v, off); }
    if (l == 0) { redA[w] = a; redV[w] = v; }
    __syncthreads();
    if (e == 0) {
        bqk[c] = redA[0] + redA[1] + redA[2] + redA[3];
        bfull[c] = bc[c] + redV[0] + redV[1] + redV[2] + redV[3];
    }
}

#define FMA44(a4, b4)                                                       \
    do {                                                                    \
        acc[0][0] += (a4).x * (b4).x; acc[0][1] += (a4).x * (b4).y;         \
        acc[0][2] += (a4).x * (b4).z; acc[0][3] += (a4).x * (b4).w;         \
        acc[1][0] += (a4).y * (b4).x; acc[1][1] += (a4).y * (b4).y;         \
        acc[1][2] += (a4).y * (b4).z; acc[1][3] += (a4).y * (b4).w;         \
        acc[2][0] += (a4).z * (b4).x; acc[2][1] += (a4).z * (b4).y;         \
        acc[2][2] += (a4).z * (b4).z; acc[2][3] += (a4).z * (b4).w;         \
        acc[3][0] += (a4).w * (b4).x; acc[3][1] += (a4).w * (b4).y;         \
        acc[3][2] += (a4).w * (b4).z; acc[3][3] += (a4).w * (b4).w;         \
    } while (0)

// ---------------- tiled M=16 x N=256 GEMM, LDS-staged B (double-buffered) --
// 256 thr: tx = t&63 (4 cols each), ty = t>>6 (4 rows each). k-step 16.
// B-tile (16x256 = 16 KB) staged cooperatively -> each element reused 16x.
// A (16 x KT) staged transposed once (stride 20; a4 read is wave-broadcast).
// One barrier per k-step; global prefetch of next B-tile hides L2 latency
// under the 256-FMA compute of the current tile.
// MODE 0: +bias. MODE 1: +bias, tanh, row-normalize (full row in one wave).
template <int KT, bool GATHER, int MODE>
__global__ __launch_bounds__(256) void gemm16t(const float* __restrict__ A,
                                               const int* __restrict__ rowidx,
                                               const float* __restrict__ B,
                                               const float* __restrict__ bias,
                                               float* __restrict__ C) {
    constexpr int NS = KT / 16;
    __shared__ float sA[KT * 20];        // [k][r], stride 20
    __shared__ float sB[2][16 * 256];    // [k][c], 16 KB each
    const int t = threadIdx.x;
    const int tx = t & 63, ty = t >> 6;
    const int col4 = tx * 4;
    const int row0 = blockIdx.x * 16;

    // stage A transposed, once
    {
        const int r = t & 15;
        const int k0 = (t >> 4) * (KT / 16);
        const size_t arow = (size_t)(GATHER ? rowidx[row0 + r] : (row0 + r)) * KT;
#pragma unroll
        for (int u = 0; u < KT / 64; ++u) {
            const float4 v = *reinterpret_cast<const float4*>(&A[arow + k0 + u * 4]);
            sA[(k0 + u * 4 + 0) * 20 + r] = v.x;
            sA[(k0 + u * 4 + 1) * 20 + r] = v.y;
            sA[(k0 + u * 4 + 2) * 20 + r] = v.z;
            sA[(k0 + u * 4 + 3) * 20 + r] = v.w;
        }
    }
    // stage B tile 0: wave ty stages rows ty*4..ty*4+3 (1 KB coalesced each)
#pragma unroll
    for (int p = 0; p < 4; ++p)
        *reinterpret_cast<float4*>(&sB[0][(ty * 4 + p) * 256 + col4]) =
            *reinterpret_cast<const float4*>(&B[(size_t)(ty * 4 + p) * 256 + col4]);
    __syncthreads();

    float acc[4][4] = {};
    float4 pb[4];
    for (int s = 0; s < NS; ++s) {
        const int cur = s & 1;
        if (s + 1 < NS) {
            const float* Bn = B + (size_t)(s + 1) * 16 * 256;
#pragma unroll
            for (int p = 0; p < 4; ++p)
                pb[p] = *reinterpret_cast<const float4*>(
                    &Bn[(size_t)(ty * 4 + p) * 256 + col4]);
        }
#pragma unroll
        for (int k = 0; k < 16; ++k) {
            const float4 a4 = *reinterpret_cast<const float4*>(&sA[(s * 16 + k) * 20 + ty * 4]);
            const float4 b4 = *reinterpret_cast<const float4*>(&sB[cur][k * 256 + col4]);
            FMA44(a4, b4);
        }
        if (s + 1 < NS) {
#pragma unroll
            for (int p = 0; p < 4; ++p)
                *reinterpret_cast<float4*>(&sB[cur ^ 1][(ty * 4 + p) * 256 + col4]) = pb[p];
        }
        __syncthreads();
    }

    // epilogue: rows row0 + ty*4 + i, cols col4..col4+3
#pragma unroll
    for (int i = 0; i < 4; ++i) {
        float v0 = acc[i][0] + bias[col4 + 0];
        float v1 = acc[i][1] + bias[col4 + 1];
        float v2 = acc[i][2] + bias[col4 + 2];
        float v3 = acc[i][3] + bias[col4 + 3];
        if (MODE == 1) {
            v0 = tanhf(v0); v1 = tanhf(v1); v2 = tanhf(v2); v3 = tanhf(v3);
            float p = v0 * v0 + v1 * v1 + v2 * v2 + v3 * v3;
#pragma unroll
            for (int off = 32; off; off >>= 1) p += __shfl_xor(p, off);
            const float invn = 1.0f / fmaxf(sqrtf(p), 1e-12f);
            v0 *= invn; v1 *= invn; v2 *= invn; v3 *= invn;
        }
        *reinterpret_cast<float4*>(&C[(size_t)(row0 + ty * 4 + i) * 256 + col4]) =
            make_float4(v0, v1, v2, v3);
    }
}

// ---------------- per-node: neighbor mean + attention-weighted sum ---------
// (R5's proven high-occupancy kernel: grid B, 1 node/block, rows in registers)
__global__ __launch_bounds__(256) void mean_attn(const float* __restrict__ id2feat,
                                                 const int* __restrict__ neigh_mean,
                                                 const int* __restrict__ neigh_attn,
                                                 const float* __restrict__ Qk,
                                                 float* __restrict__ AF) {
    const int b = blockIdx.x;
    const int t = threadIdx.x;
    const int w = t >> 6, l = t & 63;
    __shared__ int sIA[S_NEI], sIM[S_NEI];
    __shared__ float sS[S_NEI];
    __shared__ float4 sRed[2][4][64];  // 8 KB

    if (t < S_NEI) sIA[t] = neigh_attn[b * S_NEI + t];
    else if (t < 2 * S_NEI) sIM[t - S_NEI] = neigh_mean[b * S_NEI + (t - S_NEI)];
    __syncthreads();

    const float4* f4 = reinterpret_cast<const float4*>(id2feat);  // row = 64 float4
    float4 r[8];
#pragma unroll
    for (int j = 0; j < 8; ++j) r[j] = f4[(size_t)sIA[w * 8 + j] * 64 + l];
    float4 macc = make_float4(0.f, 0.f, 0.f, 0.f);
#pragma unroll
    for (int j = 0; j < 8; ++j) {
        const float4 v = f4[(size_t)sIM[w * 8 + j] * 64 + l];
        macc.x += v.x; macc.y += v.y; macc.z += v.z; macc.w += v.w;
    }
    const float4 q = reinterpret_cast<const float4*>(Qk + (size_t)b * 256)[l];

#pragma unroll
    for (int j = 0; j < 8; ++j) {
        float p = q.x * r[j].x + q.y * r[j].y + q.z * r[j].z + q.w * r[j].w;
#pragma unroll
        for (int off = 32; off; off >>= 1) p += __shfl_xor(p, off);
        if (l == 0) sS[w * 8 + j] = p;
    }
    __syncthreads();

    float m = -1e30f;
#pragma unroll
    for (int s = 0; s < S_NEI; ++s) m = fmaxf(m, sS[s]);
    float sum = 0.f;
#pragma unroll
    for (int s = 0; s < S_NEI; ++s) sum += __expf(sS[s] - m);
    const float inv = 1.0f / sum;

    float4 wa = make_float4(0.f, 0.f, 0.f, 0.f);
#pragma unroll
    for (int j = 0; j < 8; ++j) {
        const float wgt = __expf(sS[w * 8 + j] - m);
        wa.x += wgt * r[j].x; wa.y += wgt * r[j].y; wa.z += wgt * r[j].z; wa.w += wgt * r[j].w;
    }
    sRed[0][w][l] = wa;
    sRed[1][w][l] = macc;
    __syncthreads();

    float4* AF4 = reinterpret_cast<float4*>(AF) + (size_t)b * 128;  // 128 float4/row
    if (t < 64) {
        const float4 a0 = sRed[0][0][t], a1 = sRed[0][1][t], a2 = sRed[0][2][t], a3 = sRed[0][3][t];
        AF4[t] = make_float4((a0.x + a1.x + a2.x + a3.x) * inv,
                             (a0.y + a1.y + a2.y + a3.y) * inv,
                             (a0.z + a1.z + a2.z + a3.z) * inv,
                             (a0.w + a1.w + a2.w + a3.w) * inv);
    } else if (t < 128) {
        const int g = t - 64;
        const float4 a0 = sRed[1][0][g], a1 = sRed[1][1][g], a2 = sRed[1][2][g], a3 = sRed[1][3][g];
        const float sc = 1.0f / S_NEI;
        AF4[64 + g] = make_float4((a0.x + a1.x + a2.x + a3.x) * sc,
                                  (a0.y + a1.y + a2.y + a3.y) * sc,
                                  (a0.z + a1.z + a2.z + a3.z) * sc,
                                  (a0.w + a1.w + a2.w + a3.w) * sc);
    }
}

extern "C" void kernel_launch(void* const* d_in, const int* in_sizes, int n_in,
                              void* d_out, int out_size, void* d_ws, size_t ws_size,
                              hipStream_t stream) {
    const int* nodes      = (const int*)d_in[0];
    const int* neigh_mean = (const int*)d_in[1];
    const int* neigh_attn = (const int*)d_in[2];
    const float* id2feat  = (const float*)d_in[3];
    const float* Wm = (const float*)d_in[4];
    const float* bm = (const float*)d_in[5];
    const float* Wq = (const float*)d_in[6];
    const float* bq = (const float*)d_in[7];
    const float* Wk = (const float*)d_in[8];
    // d_in[9] = bk: cancels in softmax
    const float* Wv = (const float*)d_in[10];
    const float* bv = (const float*)d_in[11];
    const float* Wc = (const float*)d_in[12];
    const float* bc = (const float*)d_in[13];
    float* out = (float*)d_out;

    const int B = in_sizes[0];  // 4096

    float* ws    = (float*)d_ws;
    float* WkT   = ws;                 // 65536
    float* Wqk   = ws + 65536;         // 65536
    float* Wvc   = ws + 131072;        // 65536 } contiguous Wfused[512][256]
    float* Wmc   = ws + 196608;        // 65536 }
    float* bqk   = ws + 262144;        // 256
    float* bfull = ws + 262400;        // 256
    float* Qk    = ws + 262656;        // B*256
    float* AF    = ws + 262656 + B * 256;  // B*512

    transpose256<<<dim3(8, 8), dim3(32, 8), 0, stream>>>(Wk, WkT);
    precompute3<<<dim3(32, 3), 256, 0, stream>>>(Wq, Wv, Wm, Wc, WkT, Wqk, Wvc, Wmc);
    bias_k<<<256, 256, 0, stream>>>(bq, bv, bm, bc, Wc, WkT, bqk, bfull);
    gemm16t<256, true, 0><<<B / 16, 256, 0, stream>>>(id2feat, nodes, Wqk, bqk, Qk);
    mean_attn<<<B, 256, 0, stream>>>(id2feat, neigh_mean, neigh_attn, Qk, AF);
    gemm16t<512, false, 1><<<B / 16, 256, 0, stream>>>(AF, nullptr, Wvc /*Wfused*/, bfull, out);
}

// Round 13
// 104.517 us; speedup vs baseline: 1.0223x; 1.0223x over previous
//
#include <hip/hip_runtime.h>
#include <math.h>

#define S_NEI 32

// ---------------- transpose 256x256 (WkT[e][f] = Wk[f][e]) ----------------
__global__ __launch_bounds__(256) void transpose256(const float* __restrict__ in,
                                                    float* __restrict__ outT) {
    __shared__ float tile[32][33];
    const int bx = blockIdx.x * 32, by = blockIdx.y * 32;
    const int x = threadIdx.x, y = threadIdx.y;  // 32 x 8
#pragma unroll
    for (int i = 0; i < 32; i += 8)
        tile[y + i][x] = in[(by + y + i) * 256 + bx + x];
    __syncthreads();
#pragma unroll
    for (int i = 0; i < 32; i += 8)
        outT[(bx + y + i) * 256 + by + x] = tile[x][y + i];
}

// ---------------- legacy 8x256 tile GEMM (for tiny precompute GEMMs) -------
template <int KT>
__device__ __forceinline__ void gemm_tile8(const float* __restrict__ A, int row0,
                                           const float* __restrict__ B,
                                           float acc[2][4], float* __restrict__ sA,
                                           float* __restrict__ sB) {
    const int t = threadIdx.x;
    const int tr = t >> 6, tc = t & 63;
    const int r = t >> 5;
    const int k1 = t & 31;
    const size_t arow = (size_t)(row0 + r) * KT;
    for (int kb = 0; kb < KT; kb += 32) {
        sA[k1 * 12 + r] = A[arow + kb + k1];
#pragma unroll
        for (int i = 0; i < 8; ++i) {
            *reinterpret_cast<float4*>(&sB[(i * 4 + tr) * 256 + tc * 4]) =
                *reinterpret_cast<const float4*>(&B[(size_t)(kb + i * 4 + tr) * 256 + tc * 4]);
        }
        __syncthreads();
#pragma unroll
        for (int k = 0; k < 32; ++k) {
            const float2 a2 = *reinterpret_cast<const float2*>(&sA[k * 12 + tr * 2]);
            const float4 b4 = *reinterpret_cast<const float4*>(&sB[k * 256 + tc * 4]);
            acc[0][0] += a2.x * b4.x; acc[0][1] += a2.x * b4.y;
            acc[0][2] += a2.x * b4.z; acc[0][3] += a2.x * b4.w;
            acc[1][0] += a2.y * b4.x; acc[1][1] += a2.y * b4.y;
            acc[1][2] += a2.y * b4.z; acc[1][3] += a2.y * b4.w;
        }
        __syncthreads();
    }
}

// Wqk=Wq@WkT, Wvc=Wv@Wc_top, Wmc=Wm@Wc_bot
__global__ __launch_bounds__(256) void precompute3(const float* __restrict__ Wq,
                                                   const float* __restrict__ Wv,
                                                   const float* __restrict__ Wm,
                                                   const float* __restrict__ Wc,
                                                   const float* __restrict__ WkT,
                                                   float* __restrict__ Wqk,
                                                   float* __restrict__ Wvc,
                                                   float* __restrict__ Wmc) {
    __shared__ float sA[32 * 12];
    __shared__ float sB[32 * 256];
    float acc[2][4] = {};
    const float *Ap, *Bp;
    float* Cp;
    switch (blockIdx.y) {
        case 0: Ap = Wq; Bp = WkT; Cp = Wqk; break;
        case 1: Ap = Wv; Bp = Wc; Cp = Wvc; break;
        default: Ap = Wm; Bp = Wc + 256 * 256; Cp = Wmc; break;
    }
    const int row0 = blockIdx.x * 8;
    gemm_tile8<256>(Ap, row0, Bp, acc, sA, sB);
    const int tr = threadIdx.x >> 6, tc = threadIdx.x & 63;
#pragma unroll
    for (int i = 0; i < 2; ++i) {
        float4 v = make_float4(acc[i][0], acc[i][1], acc[i][2], acc[i][3]);
        *reinterpret_cast<float4*>(&Cp[(row0 + tr * 2 + i) * 256 + tc * 4]) = v;
    }
}

// bqk = bq@WkT ; bfull = bv@Wc_top + bm@Wc_bot + bc  (block per column)
__global__ __launch_bounds__(256) void bias_k(const float* __restrict__ bq,
                                              const float* __restrict__ bv,
                                              const float* __restrict__ bm,
                                              const float* __restrict__ bc,
                                              const float* __restrict__ Wc,
                                              const float* __restrict__ WkT,
                                              float* __restrict__ bqk,
                                              float* __restrict__ bfull) {
    const int c = blockIdx.x;
    const int e = threadIdx.x;
    const int w = e >> 6, l = e & 63;
    float a = bq[e] * WkT[e * 256 + c];
    float v = bv[e] * Wc[e * 256 + c] + bm[e] * Wc[(256 + e) * 256 + c];
    __shared__ float redA[4], redV[4];
#pragma unroll
    for (int off = 32; off; off >>= 1) { a += __shfl_xor(a, off); v += __shfl_xor(v, off); }
    if (l == 0) { redA[w] = a; redV[w] = v; }
    __syncthreads();
    if (e == 0) {
        bqk[c] = redA[0] + redA[1] + redA[2] + redA[3];
        bfull[c] = bc[c] + redV[0] + redV[1] + redV[2] + redV[3];
    }
}

#define FMA44(a4, b4)                                                       \
    do {                                                                    \
        acc[0][0] += (a4).x * (b4).x; acc[0][1] += (a4).x * (b4).y;         \
        acc[0][2] += (a4).x * (b4).z; acc[0][3] += (a4).x * (b4).w;         \
        acc[1][0] += (a4).y * (b4).x; acc[1][1] += (a4).y * (b4).y;         \
        acc[1][2] += (a4).y * (b4).z; acc[1][3] += (a4).y * (b4).w;         \
        acc[2][0] += (a4).z * (b4).x; acc[2][1] += (a4).z * (b4).y;         \
        acc[2][2] += (a4).z * (b4).z; acc[2][3] += (a4).z * (b4).w;         \
        acc[3][0] += (a4).w * (b4).x; acc[3][1] += (a4).w * (b4).y;         \
        acc[3][2] += (a4).w * (b4).z; acc[3][3] += (a4).w * (b4).w;         \
    } while (0)

// ---------------- tiled M=16 x N=256 GEMM, LDS-staged B (double-buffered) --
template <int KT, bool GATHER, int MODE>
__global__ __launch_bounds__(256) void gemm16t(const float* __restrict__ A,
                                               const int* __restrict__ rowidx,
                                               const float* __restrict__ B,
                                               const float* __restrict__ bias,
                                               float* __restrict__ C) {
    constexpr int NS = KT / 16;
    __shared__ float sA[KT * 20];        // [k][r], stride 20
    __shared__ float sB[2][16 * 256];    // [k][c], 16 KB each
    const int t = threadIdx.x;
    const int tx = t & 63, ty = t >> 6;
    const int col4 = tx * 4;
    const int row0 = blockIdx.x * 16;

    // stage A transposed, once
    {
        const int r = t & 15;
        const int k0 = (t >> 4) * (KT / 16);
        const size_t arow = (size_t)(GATHER ? rowidx[row0 + r] : (row0 + r)) * KT;
#pragma unroll
        for (int u = 0; u < KT / 64; ++u) {
            const float4 v = *reinterpret_cast<const float4*>(&A[arow + k0 + u * 4]);
            sA[(k0 + u * 4 + 0) * 20 + r] = v.x;
            sA[(k0 + u * 4 + 1) * 20 + r] = v.y;
            sA[(k0 + u * 4 + 2) * 20 + r] = v.z;
            sA[(k0 + u * 4 + 3) * 20 + r] = v.w;
        }
    }
#pragma unroll
    for (int p = 0; p < 4; ++p)
        *reinterpret_cast<float4*>(&sB[0][(ty * 4 + p) * 256 + col4]) =
            *reinterpret_cast<const float4*>(&B[(size_t)(ty * 4 + p) * 256 + col4]);
    __syncthreads();

    float acc[4][4] = {};
    float4 pb[4];
    for (int s = 0; s < NS; ++s) {
        const int cur = s & 1;
        if (s + 1 < NS) {
            const float* Bn = B + (size_t)(s + 1) * 16 * 256;
#pragma unroll
            for (int p = 0; p < 4; ++p)
                pb[p] = *reinterpret_cast<const float4*>(
                    &Bn[(size_t)(ty * 4 + p) * 256 + col4]);
        }
#pragma unroll
        for (int k = 0; k < 16; ++k) {
            const float4 a4 = *reinterpret_cast<const float4*>(&sA[(s * 16 + k) * 20 + ty * 4]);
            const float4 b4 = *reinterpret_cast<const float4*>(&sB[cur][k * 256 + col4]);
            FMA44(a4, b4);
        }
        if (s + 1 < NS) {
#pragma unroll
            for (int p = 0; p < 4; ++p)
                *reinterpret_cast<float4*>(&sB[cur ^ 1][(ty * 4 + p) * 256 + col4]) = pb[p];
        }
        __syncthreads();
    }

#pragma unroll
    for (int i = 0; i < 4; ++i) {
        float v0 = acc[i][0] + bias[col4 + 0];
        float v1 = acc[i][1] + bias[col4 + 1];
        float v2 = acc[i][2] + bias[col4 + 2];
        float v3 = acc[i][3] + bias[col4 + 3];
        if (MODE == 1) {
            v0 = tanhf(v0); v1 = tanhf(v1); v2 = tanhf(v2); v3 = tanhf(v3);
            float p = v0 * v0 + v1 * v1 + v2 * v2 + v3 * v3;
#pragma unroll
            for (int off = 32; off; off >>= 1) p += __shfl_xor(p, off);
            const float invn = 1.0f / fmaxf(sqrtf(p), 1e-12f);
            v0 *= invn; v1 *= invn; v2 *= invn; v3 *= invn;
        }
        *reinterpret_cast<float4*>(&C[(size_t)(row0 + ty * 4 + i) * 256 + col4]) =
            make_float4(v0, v1, v2, v3);
    }
}

// ---------------- mega-gather: one block per (node, {attn|mean}) -----------
// Interleaved: bid&1==0 -> attn for node bid>>1, else mean for node bid>>1.
// Tiny LDS (~4 KB), low VGPR -> ~8 blocks/CU = 32 waves/CU; each wave keeps
// 8 coalesced 1KB row-reads in flight. Wave-uniform index loads (scalar).
__global__ __launch_bounds__(256) void mega_gather(const float* __restrict__ id2feat,
                                                   const int* __restrict__ neigh_mean,
                                                   const int* __restrict__ neigh_attn,
                                                   const float* __restrict__ Qk,
                                                   float* __restrict__ AF) {
    const int bid = blockIdx.x;
    const int b = bid >> 1;
    const int t = threadIdx.x;
    const int w = t >> 6, l = t & 63;
    const float4* f4 = reinterpret_cast<const float4*>(id2feat);  // row = 64 float4
    __shared__ float4 sRed[4][64];   // 4 KB
    __shared__ float sS[S_NEI];

    if ((bid & 1) == 0) {
        // ---- attn block ----
        const int* ia = neigh_attn + (size_t)b * S_NEI + w * 8;
        float4 r[8];
#pragma unroll
        for (int j = 0; j < 8; ++j) r[j] = f4[(size_t)ia[j] * 64 + l];
        const float4 q = reinterpret_cast<const float4*>(Qk + (size_t)b * 256)[l];
#pragma unroll
        for (int j = 0; j < 8; ++j) {
            float p = q.x * r[j].x + q.y * r[j].y + q.z * r[j].z + q.w * r[j].w;
#pragma unroll
            for (int off = 32; off; off >>= 1) p += __shfl_xor(p, off);
            if (l == 0) sS[w * 8 + j] = p;
        }
        __syncthreads();
        float m = -1e30f;
#pragma unroll
        for (int s = 0; s < S_NEI; ++s) m = fmaxf(m, sS[s]);
        float sum = 0.f;
#pragma unroll
        for (int s = 0; s < S_NEI; ++s) sum += __expf(sS[s] - m);
        const float inv = 1.0f / sum;
        float4 wa = make_float4(0.f, 0.f, 0.f, 0.f);
#pragma unroll
        for (int j = 0; j < 8; ++j) {
            const float g = __expf(sS[w * 8 + j] - m);
            wa.x += g * r[j].x; wa.y += g * r[j].y;
            wa.z += g * r[j].z; wa.w += g * r[j].w;
        }
        sRed[w][l] = wa;
        __syncthreads();
        if (t < 64) {
            const float4 a0 = sRed[0][t], a1 = sRed[1][t], a2 = sRed[2][t], a3 = sRed[3][t];
            reinterpret_cast<float4*>(AF + (size_t)b * 512)[t] =
                make_float4((a0.x + a1.x + a2.x + a3.x) * inv,
                            (a0.y + a1.y + a2.y + a3.y) * inv,
                            (a0.z + a1.z + a2.z + a3.z) * inv,
                            (a0.w + a1.w + a2.w + a3.w) * inv);
        }
    } else {
        // ---- mean block ----
        const int* im = neigh_mean + (size_t)b * S_NEI + w * 8;
        float4 macc = make_float4(0.f, 0.f, 0.f, 0.f);
#pragma unroll
        for (int j = 0; j < 8; ++j) {
            const float4 v = f4[(size_t)im[j] * 64 + l];
            macc.x += v.x; macc.y += v.y; macc.z += v.z; macc.w += v.w;
        }
        sRed[w][l] = macc;
        __syncthreads();
        if (t < 64) {
            const float4 a0 = sRed[0][t], a1 = sRed[1][t], a2 = sRed[2][t], a3 = sRed[3][t];
            const float sc = 1.0f / S_NEI;
            reinterpret_cast<float4*>(AF + (size_t)b * 512 + 256)[t] =
                make_float4((a0.x + a1.x + a2.x + a3.x) * sc,
                            (a0.y + a1.y + a2.y + a3.y) * sc,
                            (a0.z + a1.z + a2.z + a3.z) * sc,
                            (a0.w + a1.w + a2.w + a3.w) * sc);
        }
    }
}

extern "C" void kernel_launch(void* const* d_in, const int* in_sizes, int n_in,
                              void* d_out, int out_size, void* d_ws, size_t ws_size,
                              hipStream_t stream) {
    const int* nodes      = (const int*)d_in[0];
    const int* neigh_mean = (const int*)d_in[1];
    const int* neigh_attn = (const int*)d_in[2];
    const float* id2feat  = (const float*)d_in[3];
    const float* Wm = (const float*)d_in[4];
    const float* bm = (const float*)d_in[5];
    const float* Wq = (const float*)d_in[6];
    const float* bq = (const float*)d_in[7];
    const float* Wk = (const float*)d_in[8];
    // d_in[9] = bk: cancels in softmax
    const float* Wv = (const float*)d_in[10];
    const float* bv = (const float*)d_in[11];
    const float* Wc = (const float*)d_in[12];
    const float* bc = (const float*)d_in[13];
    float* out = (float*)d_out;

    const int B = in_sizes[0];  // 4096

    float* ws    = (float*)d_ws;
    float* WkT   = ws;                 // 65536
    float* Wqk   = ws + 65536;         // 65536
    float* Wvc   = ws + 131072;        // 65536 } contiguous Wfused[512][256]
    float* Wmc   = ws + 196608;        // 65536 }
    float* bqk   = ws + 262144;        // 256
    float* bfull = ws + 262400;        // 256
    float* Qk    = ws + 262656;        // B*256
    float* AF    = ws + 262656 + B * 256;  // B*512

    transpose256<<<dim3(8, 8), dim3(32, 8), 0, stream>>>(Wk, WkT);
    precompute3<<<dim3(32, 3), 256, 0, stream>>>(Wq, Wv, Wm, Wc, WkT, Wqk, Wvc, Wmc);
    bias_k<<<256, 256, 0, stream>>>(bq, bv, bm, bc, Wc, WkT, bqk, bfull);
    gemm16t<256, true, 0><<<B / 16, 256, 0, stream>>>(id2feat, nodes, Wqk, bqk, Qk);
    mega_gather<<<2 * B, 256, 0, stream>>>(id2feat, neigh_mean, neigh_attn, Qk, AF);
    gemm16t<512, false, 1><<<B / 16, 256, 0, stream>>>(AF, nullptr, Wvc /*Wfused*/, bfull, out);
}